// Round 1
// baseline (267.729 us; speedup 1.0000x reference)
//
#include <hip/hip_runtime.h>

// Problem constants (match reference): B=16, T=4096, E=768.
constexpr int Bc = 16;
constexpr int Tc = 4096;
constexpr int Ec = 768;
constexpr int PSTRIDE = Ec + 2;   // per-partial: [m, l, o[768]]

// Fast accurate-enough tanh: tanh(x) = (e^2x - 1)/(e^2x + 1), v_exp + v_rcp.
__device__ __forceinline__ float fast_tanh(float x) {
    x = fminf(15.0f, fmaxf(-15.0f, x));           // avoid inf/inf
    float e = __expf(2.0f * x);                   // v_exp_f32 path
    return (e - 1.0f) * __builtin_amdgcn_rcpf(e + 1.0f);
}

__device__ __forceinline__ float dot_tanh4(float4 c, float4 w) {
    float s;
    s = fast_tanh(c.x) * w.x;
    s = fmaf(fast_tanh(c.y), w.y, s);
    s = fmaf(fast_tanh(c.z), w.z, s);
    s = fmaf(fast_tanh(c.w), w.w, s);
    return s;
}

__device__ __forceinline__ float4 upd4(float4 o, float alpha, float p, float4 c) {
    return make_float4(fmaf(o.x, alpha, p * c.x),
                       fmaf(o.y, alpha, p * c.y),
                       fmaf(o.z, alpha, p * c.z),
                       fmaf(o.w, alpha, p * c.w));
}

// Kernel 1: per (b, chunk) block, flash-style online softmax-weighted sum over
// the chunk's rows. One wave per row-group; each lane holds e = j*256 + 4*lane..+3.
// Softmax shift-invariance => the tanh(query)·v_w[:E] term is dropped (exact).
// Masked rows (mask==0) are skipped entirely (exact: exp(-1e10 - m) == 0 in fp32).
template<int C>
__global__ __launch_bounds__(256) void attn_partial(
    const float* __restrict__ ctx, const int* __restrict__ mask,
    const float* __restrict__ v_w, float* __restrict__ ws)
{
    constexpr int ROWS_PER_BLOCK = Tc / C;
    constexpr int R = ROWS_PER_BLOCK / 4;     // rows per wave
    const int b    = blockIdx.x / C;
    const int c    = blockIdx.x % C;
    const int wave = threadIdx.x >> 6;
    const int lane = threadIdx.x & 63;

    // Preload second half of v_w for this lane's e-slice.
    float4 vw[3];
#pragma unroll
    for (int j = 0; j < 3; ++j)
        vw[j] = *reinterpret_cast<const float4*>(v_w + Ec + j * 256 + 4 * lane);

    float m = -1e30f, l = 0.0f;
    float4 o0 = make_float4(0.f, 0.f, 0.f, 0.f), o1 = o0, o2 = o0;

    const int  row0  = c * ROWS_PER_BLOCK + wave * R;
    const long cbase = (long)b * Tc * Ec;

    for (int g = 0; g < R; g += 64) {
        // Prefetch up to 64 row masks across lanes; broadcast via shfl.
        int tl = row0 + g + lane;
        tl = tl < (Tc - 1) ? tl : (Tc - 1);
        const int mv = mask[b * Tc + tl];
        const int nr = (R - g < 64) ? (R - g) : 64;
        for (int r = 0; r < nr; ++r) {
            if (__shfl(mv, r, 64) == 0) continue;   // wave-uniform skip
            const int t = row0 + g + r;
            const float* rowp = ctx + cbase + (long)t * Ec + 4 * lane;
            float4 cv0 = *reinterpret_cast<const float4*>(rowp);
            float4 cv1 = *reinterpret_cast<const float4*>(rowp + 256);
            float4 cv2 = *reinterpret_cast<const float4*>(rowp + 512);

            float s = dot_tanh4(cv0, vw[0]);
            s += dot_tanh4(cv1, vw[1]);
            s += dot_tanh4(cv2, vw[2]);
#pragma unroll
            for (int off = 32; off > 0; off >>= 1)
                s += __shfl_xor(s, off, 64);        // all lanes get the score

            float mn    = fmaxf(m, s);
            float alpha = __expf(m - mn);
            float p     = __expf(s - mn);
            l  = fmaf(l, alpha, p);
            o0 = upd4(o0, alpha, p, cv0);
            o1 = upd4(o1, alpha, p, cv1);
            o2 = upd4(o2, alpha, p, cv2);
            m  = mn;
        }
    }

    // Combine the block's 4 wave partials in LDS, write one block partial.
    __shared__ float sm[4], sl[4];
    __shared__ float so[4][Ec];
    if (lane == 0) { sm[wave] = m; sl[wave] = l; }
    __syncthreads();
    float M = fmaxf(fmaxf(sm[0], sm[1]), fmaxf(sm[2], sm[3]));
    float wscale = __expf(m - M);   // m is wave-uniform
    {
        float4 t0 = make_float4(o0.x * wscale, o0.y * wscale, o0.z * wscale, o0.w * wscale);
        float4 t1 = make_float4(o1.x * wscale, o1.y * wscale, o1.z * wscale, o1.w * wscale);
        float4 t2 = make_float4(o2.x * wscale, o2.y * wscale, o2.z * wscale, o2.w * wscale);
        *reinterpret_cast<float4*>(&so[wave][0 * 256 + 4 * lane]) = t0;
        *reinterpret_cast<float4*>(&so[wave][1 * 256 + 4 * lane]) = t1;
        *reinterpret_cast<float4*>(&so[wave][2 * 256 + 4 * lane]) = t2;
    }
    __syncthreads();

    float* part = ws + ((long)b * C + c) * PSTRIDE;
    if (threadIdx.x == 0) {
        part[0] = M;
        part[1] = sl[0] * __expf(sm[0] - M) + sl[1] * __expf(sm[1] - M)
                + sl[2] * __expf(sm[2] - M) + sl[3] * __expf(sm[3] - M);
    }
#pragma unroll
    for (int j = 0; j < 3; ++j) {
        int e = threadIdx.x + j * 256;
        part[2 + e] = so[0][e] + so[1][e] + so[2][e] + so[3][e];
    }
}

// Kernel 2: combine C partials per batch row with global rescale.
// grid = (B, 3): each block handles 256 output features.
template<int C>
__global__ __launch_bounds__(256) void attn_reduce(
    const float* __restrict__ ws, float* __restrict__ out)
{
    const int b   = blockIdx.x;
    const int j   = blockIdx.y;
    const int tid = threadIdx.x;
    __shared__ float sm[C], sw[C], swl[C];
    const float* pb = ws + (long)b * C * PSTRIDE;

    if (tid < C) sm[tid] = pb[tid * PSTRIDE];
    __syncthreads();
    float M = -1e30f;
    for (int k = 0; k < C; ++k) M = fmaxf(M, sm[k]);
    if (tid < C) {
        float wv = __expf(sm[tid] - M);
        sw[tid]  = wv;
        swl[tid] = wv * pb[tid * PSTRIDE + 1];
    }
    __syncthreads();

    float lsum = 0.f;
    for (int k = 0; k < C; ++k) lsum += swl[k];

    const int e = j * 256 + tid;
    float acc = 0.f;
    for (int k = 0; k < C; ++k)
        acc = fmaf(sw[k], pb[k * PSTRIDE + 2 + e], acc);

    out[b * Ec + e] = acc * __builtin_amdgcn_rcpf(lsum);
}

template<int C>
static void run_pipeline(const float* ctx, const int* mask, const float* vw,
                         float* ws, float* out, hipStream_t stream)
{
    attn_partial<C><<<dim3(Bc * C), 256, 0, stream>>>(ctx, mask, vw, ws);
    attn_reduce<C><<<dim3(Bc, 3), 256, 0, stream>>>(ws, out);
}

extern "C" void kernel_launch(void* const* d_in, const int* in_sizes, int n_in,
                              void* d_out, int out_size, void* d_ws, size_t ws_size,
                              hipStream_t stream)
{
    (void)in_sizes; (void)n_in; (void)out_size;
    // setup_inputs order: query[0] (unused — softmax shift-invariant),
    // context[1], mask[2], v_w[3].
    const float* ctx  = (const float*)d_in[1];
    const int*   mask = (const int*)d_in[2];
    const float* vw   = (const float*)d_in[3];
    float* out = (float*)d_out;
    float* ws  = (float*)d_ws;

    const size_t need64 = (size_t)Bc * 64 * PSTRIDE * sizeof(float);
    const size_t need16 = (size_t)Bc * 16 * PSTRIDE * sizeof(float);
    const size_t need4  = (size_t)Bc * 4  * PSTRIDE * sizeof(float);

    if (ws_size >= need64)      run_pipeline<64>(ctx, mask, vw, ws, out, stream);
    else if (ws_size >= need16) run_pipeline<16>(ctx, mask, vw, ws, out, stream);
    else if (ws_size >= need4)  run_pipeline<4>(ctx, mask, vw, ws, out, stream);
    else                        run_pipeline<1>(ctx, mask, vw, ws, out, stream);
}